// Round 4
// baseline (397.458 us; speedup 1.0000x reference)
//
#include <hip/hip_runtime.h>

#define HCC 128
#define NEG_SLOPE 0.2f
#define CHUNK 16

// ---------------- edge_attr sum (for mean self-loop fill) ----------------
__global__ void ea_reduce_kernel(const float* __restrict__ ea, float* __restrict__ sum, int E) {
  float acc = 0.f;
  for (int i = blockIdx.x * blockDim.x + threadIdx.x; i < E; i += gridDim.x * blockDim.x)
    acc += ea[i];
  #pragma unroll
  for (int off = 32; off > 0; off >>= 1) acc += __shfl_down(acc, off);
  if ((threadIdx.x & 63) == 0) atomicAdd(sum, acc);
}

// ---------------- degree count over edges + self loops ----------------
__global__ void deg_count_kernel(const int* __restrict__ ei, int* __restrict__ deg, int E, int N) {
  int k = blockIdx.x * blockDim.x + threadIdx.x;
  if (k >= E + N) return;
  int t = (k < E) ? ei[E + k] : (k - E);
  atomicAdd(&deg[t], 1);
}

// ---------------- exclusive scan (single block, 1024 threads) ----------------
__global__ void scan_kernel(const int* __restrict__ deg, int* __restrict__ offs, int n) {
  __shared__ int wsum[16];
  int carry = 0;  // only thread 0's copy is meaningful
  for (int base = 0; base < n; base += 1024) {
    int i = base + (int)threadIdx.x;
    int v = (i < n) ? deg[i] : 0;
    int lane = threadIdx.x & 63, wid = threadIdx.x >> 6;
    int x = v;
    #pragma unroll
    for (int off = 1; off < 64; off <<= 1) {
      int y = __shfl_up(x, off);
      if (lane >= off) x += y;
    }
    if (lane == 63) wsum[wid] = x;
    __syncthreads();
    if (threadIdx.x == 0) {
      int run = carry;
      #pragma unroll
      for (int w2 = 0; w2 < 16; w2++) { int tv = wsum[w2]; wsum[w2] = run; run += tv; }
      carry = run;
    }
    __syncthreads();
    if (i < n) offs[i] = x - v + wsum[wid];
    __syncthreads();  // protect wsum before next chunk overwrites it
  }
  if (threadIdx.x == 0) offs[n] = carry;
}

// ---------------- scatter edges into CSR-by-target ----------------
__global__ void scatter_kernel(const int* __restrict__ ei, const float* __restrict__ ea,
                               const float* __restrict__ ea_sum, const int* __restrict__ offs,
                               int* __restrict__ cursor, int* __restrict__ csr_src,
                               float* __restrict__ csr_ea, int E, int N) {
  int k = blockIdx.x * blockDim.x + threadIdx.x;
  if (k >= E + N) return;
  int s, t; float v;
  if (k < E) { s = ei[k]; t = ei[E + k]; v = ea[k]; }
  else       { s = t = k - E; v = ea_sum[0] * (1.0f / (float)E); }
  int pos = offs[t] + atomicAdd(&cursor[t], 1);
  csr_src[pos] = s;
  csr_ea[pos] = v;
}

// ---------------- GATv2 layer 1, specialized for x of shape (N,1) ----------------
// Rank-1 structure: out[c] = Wl[c]*(sum_e a_e x_s) + bl[c] + bias[c].
// Chunk-16 batched scalar gathers for memory-level parallelism.
__global__ void gat1_kernel(const float* __restrict__ x,
    const int* __restrict__ offs, const int* __restrict__ csr_src,
    const float* __restrict__ csr_ea,
    const float* __restrict__ Wl, const float* __restrict__ bl,
    const float* __restrict__ Wr, const float* __restrict__ br,
    const float* __restrict__ We, const float* __restrict__ att,
    const float* __restrict__ bias, float* __restrict__ outh, int N) {
  int t = (blockIdx.x * blockDim.x + threadIdx.x) >> 6;
  if (t >= N) return;
  int lane = threadIdx.x & 63;
  int c = lane * 2;
  float2 wl = *(const float2*)&Wl[c];
  float2 wr = *(const float2*)&Wr[c];
  float2 we = *(const float2*)&We[c];
  float2 at = *(const float2*)&att[c];
  float2 bl2 = *(const float2*)&bl[c];
  float2 br2 = *(const float2*)&br[c];
  float xt = x[t];
  float base0 = fmaf(xt, wr.x, br2.x + bl2.x);
  float base1 = fmaf(xt, wr.y, br2.y + bl2.y);
  int e0 = offs[t], e1 = offs[t + 1];

  float mx = -1e30f, den = 0.f, S1 = 0.f;
  for (int base = e0; base < e1; base += CHUNK) {
    float xs[CHUNK], eav[CHUNK];
    #pragma unroll
    for (int q = 0; q < CHUNK; q++) {
      int e = base + q;
      int ec = e < e1 ? e : e1 - 1;   // wave-uniform clamp; all loads issue
      int s = csr_src[ec];
      eav[q] = csr_ea[ec];
      xs[q] = x[s];
    }
    #pragma unroll
    for (int q = 0; q < CHUNK; q++) {
      float m0 = fmaf(xs[q], wl.x, fmaf(eav[q], we.x, base0));
      float m1 = fmaf(xs[q], wl.y, fmaf(eav[q], we.y, base1));
      m0 = m0 > 0.f ? m0 : NEG_SLOPE * m0;
      m1 = m1 > 0.f ? m1 : NEG_SLOPE * m1;
      float p = fmaf(m0, at.x, m1 * at.y);
      #pragma unroll
      for (int off = 1; off < 32; off <<= 1) p += __shfl_xor(p, off);
      p = (base + q < e1) ? p : -1e30f;   // mask tail: wgt->0, scale->1
      float d = p - mx;
      float ed = __expf(-fabsf(d));
      float scale = d > 0.f ? ed : 1.f;
      float wgt = d > 0.f ? 1.f : ed;
      mx = fmaxf(mx, p);
      den = fmaf(den, scale, wgt);
      S1 = fmaf(S1, scale, wgt * xs[q]);
    }
  }
  float T = S1 / den;
  float2 bv = *(const float2*)&bias[c];
  float o0 = fmaxf(fmaf(wl.x, T, bl2.x + bv.x), 0.f);
  float o1 = fmaxf(fmaf(wl.y, T, bl2.y + bv.y), 0.f);
  *(float2*)&outh[(size_t)t * HCC + c] = make_float2(o0, o1);
}

// ---------------- GATv2 layer 2: one wave per node, online softmax ----------------
// Chunk-16 batched row gathers: 16 independent load chains in flight per wave.
__global__ void gat2_kernel(const float* __restrict__ xl, const float* __restrict__ xr,
    const int* __restrict__ offs, const int* __restrict__ csr_src,
    const float* __restrict__ csr_ea,
    const float* __restrict__ We, const float* __restrict__ att,
    const float* __restrict__ bias, float* __restrict__ outh, int N) {
  int t = (blockIdx.x * blockDim.x + threadIdx.x) >> 6;
  if (t >= N) return;
  int lane = threadIdx.x & 63;
  int c = lane * 2;
  float2 xrv = *(const float2*)&xr[(size_t)t * HCC + c];
  float2 wev = *(const float2*)&We[c];
  float2 atv = *(const float2*)&att[c];
  int e0 = offs[t], e1 = offs[t + 1];

  float mx = -1e30f, den = 0.f, a0 = 0.f, a1 = 0.f;
  for (int base = e0; base < e1; base += CHUNK) {
    float2 xj[CHUNK]; float eav[CHUNK];
    #pragma unroll
    for (int q = 0; q < CHUNK; q++) {
      int e = base + q;
      int ec = e < e1 ? e : e1 - 1;   // wave-uniform clamp
      int s = csr_src[ec];
      eav[q] = csr_ea[ec];
      xj[q] = *(const float2*)&xl[(size_t)s * HCC + c];
    }
    #pragma unroll
    for (int q = 0; q < CHUNK; q++) {
      float m0 = fmaf(eav[q], wev.x, xrv.x + xj[q].x);
      float m1 = fmaf(eav[q], wev.y, xrv.y + xj[q].y);
      m0 = m0 > 0.f ? m0 : NEG_SLOPE * m0;
      m1 = m1 > 0.f ? m1 : NEG_SLOPE * m1;
      float p = fmaf(m0, atv.x, m1 * atv.y);
      #pragma unroll
      for (int off = 1; off < 32; off <<= 1) p += __shfl_xor(p, off);
      p = (base + q < e1) ? p : -1e30f;   // mask tail
      float d = p - mx;
      float ed = __expf(-fabsf(d));
      float scale = d > 0.f ? ed : 1.f;
      float wgt = d > 0.f ? 1.f : ed;
      mx = fmaxf(mx, p);
      den = fmaf(den, scale, wgt);
      a0 = fmaf(a0, scale, wgt * xj[q].x);
      a1 = fmaf(a1, scale, wgt * xj[q].y);
    }
  }
  float inv = 1.0f / den;
  float2 bv = *(const float2*)&bias[c];
  float o0 = fmaxf(fmaf(a0, inv, bv.x), 0.f);
  float o1 = fmaxf(fmaf(a1, inv, bv.y), 0.f);
  *(float2*)&outh[(size_t)t * HCC + c] = make_float2(o0, o1);
}

// ---------------- layer-2 transforms: h1(N,128) @ {Wl,Wr}(128,128) ----------------
__global__ __launch_bounds__(256) void l2_transform_kernel(const float* __restrict__ h,
    const float* __restrict__ Wl, const float* __restrict__ bl,
    const float* __restrict__ Wr, const float* __restrict__ br,
    float* __restrict__ xl, float* __restrict__ xr, int N) {
  __shared__ float hs[16][HCC];
  __shared__ float Ws[2][32][HCC];
  int tid = threadIdx.x;
  int nbase = blockIdx.x * 16;
  for (int i = tid; i < 16 * 32; i += 256) {
    int nr = i >> 5, col = (i & 31) * 4;
    int gn = nbase + nr;
    float4 v = (gn < N) ? *(const float4*)&h[(size_t)gn * HCC + col] : make_float4(0,0,0,0);
    *(float4*)&hs[nr][col] = v;
  }
  int slot = tid >> 5;
  int c0 = (tid & 31) * 4;
  float acc[2][8];
  #pragma unroll
  for (int s = 0; s < 2; s++)
    #pragma unroll
    for (int q = 0; q < 8; q++) acc[s][q] = 0.f;

  for (int kb = 0; kb < 4; kb++) {
    __syncthreads();
    for (int i = tid; i < 2048; i += 256) {
      int mat = i >> 10;
      int idx = i & 1023;
      int krow = idx >> 5, col = (idx & 31) * 4;
      const float* src = mat ? Wr : Wl;
      *(float4*)&Ws[mat][krow][col] = *(const float4*)&src[(size_t)(kb * 32 + krow) * HCC + col];
    }
    __syncthreads();
    for (int k2 = 0; k2 < 32; k2++) {
      float4 wl4 = *(const float4*)&Ws[0][k2][c0];
      float4 wr4 = *(const float4*)&Ws[1][k2][c0];
      int kk = kb * 32 + k2;
      #pragma unroll
      for (int s = 0; s < 2; s++) {
        float hv = hs[slot + 8 * s][kk];
        acc[s][0] = fmaf(hv, wl4.x, acc[s][0]);
        acc[s][1] = fmaf(hv, wl4.y, acc[s][1]);
        acc[s][2] = fmaf(hv, wl4.z, acc[s][2]);
        acc[s][3] = fmaf(hv, wl4.w, acc[s][3]);
        acc[s][4] = fmaf(hv, wr4.x, acc[s][4]);
        acc[s][5] = fmaf(hv, wr4.y, acc[s][5]);
        acc[s][6] = fmaf(hv, wr4.z, acc[s][6]);
        acc[s][7] = fmaf(hv, wr4.w, acc[s][7]);
      }
    }
  }
  float4 blv = *(const float4*)&bl[c0];
  float4 brv = *(const float4*)&br[c0];
  #pragma unroll
  for (int s = 0; s < 2; s++) {
    int gn = nbase + slot + 8 * s;
    if (gn < N) {
      float4 o1 = make_float4(acc[s][0] + blv.x, acc[s][1] + blv.y, acc[s][2] + blv.z, acc[s][3] + blv.w);
      float4 o2 = make_float4(acc[s][4] + brv.x, acc[s][5] + brv.y, acc[s][6] + brv.z, acc[s][7] + brv.w);
      *(float4*)&xl[(size_t)gn * HCC + c0] = o1;
      *(float4*)&xr[(size_t)gn * HCC + c0] = o2;
    }
  }
}

// ---------------- msg_emb^T = (message @ fc1_W + fc1_b)^T  -> [128][256] ----------------
__global__ void msg_gemm_kernel(const float* __restrict__ msg, const float* __restrict__ W,
                                const float* __restrict__ b, float* __restrict__ memb_t) {
  int r = blockIdx.x, c = threadIdx.x;  // r = message index (0..255), c = out channel (0..127)
  const float* mrow = &msg[(size_t)r * HCC];
  float acc = b[c];
  #pragma unroll 8
  for (int k = 0; k < HCC; k++) acc = fmaf(mrow[k], W[(size_t)k * HCC + c], acc);
  memb_t[(size_t)c * 256 + r] = acc;
}

// ---------------- logits = h @ memb^T; row softmax ----------------
// 64 nodes x 256 msgs per block. ms chunked to 16 k-rows -> 48 KB LDS
// (3 blocks/CU). Thread owns col pairs {jj*64 + tx*2, +1}: float2 B reads
// (lane l & l+32 same addr = free broadcast), paired FMAs, float2 out.
__global__ __launch_bounds__(256) void logits_softmax_kernel(
    const float* __restrict__ h, const float* __restrict__ memb_t,
    float* __restrict__ out, int N) {
  __shared__ float hs[64][HCC];   // 32 KB
  __shared__ float ms[16][256];   // 16 KB  (k-chunk of memb_t)
  int tid = threadIdx.x;
  int nbase = blockIdx.x * 64;
  for (int i = tid; i < 64 * 32; i += 256) {
    int nr = i >> 5, col = (i & 31) * 4;
    int gn = nbase + nr;
    float4 v = (gn < N) ? *(const float4*)&h[(size_t)gn * HCC + col] : make_float4(0, 0, 0, 0);
    *(float4*)&hs[nr][col] = v;
  }
  int ty = tid >> 5, tx = tid & 31;
  float2 acc[8][4];
  #pragma unroll
  for (int i = 0; i < 8; i++)
    #pragma unroll
    for (int j = 0; j < 4; j++) acc[i][j] = make_float2(0.f, 0.f);

  for (int kb = 0; kb < 8; kb++) {
    __syncthreads();
    for (int i = tid; i < 1024; i += 256) {
      int kr = i >> 6, col = (i & 63) * 4;
      *(float4*)&ms[kr][col] = *(const float4*)&memb_t[(size_t)(kb * 16 + kr) * 256 + col];
    }
    __syncthreads();
    for (int kk = 0; kk < 16; kk += 4) {
      float4 a[8];
      #pragma unroll
      for (int i = 0; i < 8; i++) a[i] = *(const float4*)&hs[ty * 8 + i][kb * 16 + kk];
      #pragma unroll
      for (int q = 0; q < 4; q++) {
        float2 bv[4];
        #pragma unroll
        for (int j = 0; j < 4; j++) bv[j] = *(const float2*)&ms[kk + q][j * 64 + tx * 2];
        #pragma unroll
        for (int i = 0; i < 8; i++) {
          float av = (q == 0) ? a[i].x : (q == 1) ? a[i].y : (q == 2) ? a[i].z : a[i].w;
          #pragma unroll
          for (int j = 0; j < 4; j++) {
            acc[i][j].x = fmaf(av, bv[j].x, acc[i][j].x);
            acc[i][j].y = fmaf(av, bv[j].y, acc[i][j].y);
          }
        }
      }
    }
  }

  // per-node softmax over 256 cols: local 8 + shuffle over 32 lanes (same ty group)
  #pragma unroll
  for (int i = 0; i < 8; i++) {
    int gn = nbase + ty * 8 + i;
    float m = fmaxf(acc[i][0].x, acc[i][0].y);
    #pragma unroll
    for (int j = 1; j < 4; j++) m = fmaxf(m, fmaxf(acc[i][j].x, acc[i][j].y));
    #pragma unroll
    for (int off = 1; off < 32; off <<= 1) m = fmaxf(m, __shfl_xor(m, off));
    float2 e[4]; float s = 0.f;
    #pragma unroll
    for (int j = 0; j < 4; j++) {
      e[j].x = expf(acc[i][j].x - m);
      e[j].y = expf(acc[i][j].y - m);
      s += e[j].x + e[j].y;
    }
    #pragma unroll
    for (int off = 1; off < 32; off <<= 1) s += __shfl_xor(s, off);
    float inv = 1.0f / s;
    if (gn < N) {
      #pragma unroll
      for (int j = 0; j < 4; j++) {
        float2 o = make_float2(e[j].x * inv, e[j].y * inv);
        *(float2*)&out[(size_t)gn * 256 + j * 64 + tx * 2] = o;
      }
    }
  }
}

extern "C" void kernel_launch(void* const* d_in, const int* in_sizes, int n_in,
                              void* d_out, int out_size, void* d_ws, size_t ws_size,
                              hipStream_t stream) {
  (void)n_in; (void)out_size; (void)ws_size;
  const float* message  = (const float*)d_in[0];
  const float* x        = (const float*)d_in[1];
  const float* edge_attr= (const float*)d_in[2];
  const float* c1_Wl   = (const float*)d_in[3];
  const float* c1_bl   = (const float*)d_in[4];
  const float* c1_Wr   = (const float*)d_in[5];
  const float* c1_br   = (const float*)d_in[6];
  const float* c1_We   = (const float*)d_in[7];
  const float* c1_att  = (const float*)d_in[8];
  const float* c1_bias = (const float*)d_in[9];
  const float* c2_Wl   = (const float*)d_in[10];
  const float* c2_bl   = (const float*)d_in[11];
  const float* c2_Wr   = (const float*)d_in[12];
  const float* c2_br   = (const float*)d_in[13];
  const float* c2_We   = (const float*)d_in[14];
  const float* c2_att  = (const float*)d_in[15];
  const float* c2_bias = (const float*)d_in[16];
  const float* fc1_W   = (const float*)d_in[17];
  const float* fc1_b   = (const float*)d_in[18];
  const int* edge_index = (const int*)d_in[19];

  const int N = in_sizes[1];          // 50000
  const int E = in_sizes[2];          // 500000
  const int Et = E + N;
  const int B = in_sizes[0] / HCC;    // 256
  float* out = (float*)d_out;

  char* wsb = (char*)d_ws;
  size_t woff = 0;
  auto alloc = [&](size_t bytes) -> void* {
    void* p = wsb + woff;
    woff += (bytes + 255) & ~(size_t)255;
    return p;
  };
  float* xl     = (float*)alloc((size_t)N * HCC * 4);
  float* xr     = (float*)alloc((size_t)N * HCC * 4);
  float* hb     = (float*)alloc((size_t)N * HCC * 4);
  float* memb_t = (float*)alloc((size_t)B * HCC * 4);
  float* ea_sum = (float*)alloc(256);
  int* deg      = (int*)alloc((size_t)N * 4);
  int* offs     = (int*)alloc((size_t)(N + 1) * 4);
  int* cursor   = (int*)alloc((size_t)N * 4);
  int* csr_src  = (int*)alloc((size_t)Et * 4);
  float* csr_ea = (float*)alloc((size_t)Et * 4);

  hipMemsetAsync(ea_sum, 0, 4, stream);
  hipMemsetAsync(deg, 0, (size_t)N * 4, stream);
  hipMemsetAsync(cursor, 0, (size_t)N * 4, stream);

  ea_reduce_kernel<<<256, 256, 0, stream>>>(edge_attr, ea_sum, E);
  deg_count_kernel<<<(Et + 255) / 256, 256, 0, stream>>>(edge_index, deg, E, N);
  scan_kernel<<<1, 1024, 0, stream>>>(deg, offs, N);
  scatter_kernel<<<(Et + 255) / 256, 256, 0, stream>>>(edge_index, edge_attr, ea_sum,
                                                       offs, cursor, csr_src, csr_ea, E, N);
  gat1_kernel<<<(N + 3) / 4, 256, 0, stream>>>(x, offs, csr_src, csr_ea,
                                               c1_Wl, c1_bl, c1_Wr, c1_br,
                                               c1_We, c1_att, c1_bias, hb, N);
  l2_transform_kernel<<<(N + 15) / 16, 256, 0, stream>>>(hb, c2_Wl, c2_bl, c2_Wr, c2_br,
                                                         xl, xr, N);
  gat2_kernel<<<(N + 3) / 4, 256, 0, stream>>>(xl, xr, offs, csr_src, csr_ea,
                                               c2_We, c2_att, c2_bias, hb, N);
  msg_gemm_kernel<<<B, HCC, 0, stream>>>(message, fc1_W, fc1_b, memb_t);
  logits_softmax_kernel<<<(N + 63) / 64, 256, 0, stream>>>(hb, memb_t, out, N);
}

// Round 5
// 334.973 us; speedup vs baseline: 1.1865x; 1.1865x over previous
//
#include <hip/hip_runtime.h>

#define HCC 128
#define NEG_SLOPE 0.2f
#define CHUNK 16

// fold-reduce step: k simultaneous 32-lane reductions, halving per step.
// After FOLD(16,8),FOLD(8,4),FOLD(4,2),FOLD(2,1) + final xor1, lane l holds
// the full 32-lane sum of edge q(l) = ((l&31)>>1)&15 (each edge in 2 lanes).
#define FOLD_STEP(S, CNT)                                    \
  {                                                          \
    _Pragma("unroll")                                        \
    for (int q = 0; q < CNT; q++) {                          \
      bool hi = (lane & S) != 0;                             \
      float give = hi ? pr[q] : pr[q + CNT];                 \
      float keep = hi ? pr[q + CNT] : pr[q];                 \
      pr[q] = keep + __shfl_xor(give, S);                    \
    }                                                        \
  }

// ---------------- edge_attr sum (for mean self-loop fill) ----------------
__global__ void ea_reduce_kernel(const float* __restrict__ ea, float* __restrict__ sum, int E) {
  float acc = 0.f;
  for (int i = blockIdx.x * blockDim.x + threadIdx.x; i < E; i += gridDim.x * blockDim.x)
    acc += ea[i];
  #pragma unroll
  for (int off = 32; off > 0; off >>= 1) acc += __shfl_down(acc, off);
  if ((threadIdx.x & 63) == 0) atomicAdd(sum, acc);
}

// ---------------- degree count over edges + self loops ----------------
__global__ void deg_count_kernel(const int* __restrict__ ei, int* __restrict__ deg, int E, int N) {
  int k = blockIdx.x * blockDim.x + threadIdx.x;
  if (k >= E + N) return;
  int t = (k < E) ? ei[E + k] : (k - E);
  atomicAdd(&deg[t], 1);
}

// ---------------- exclusive scan (single block, 1024 threads) ----------------
__global__ void scan_kernel(const int* __restrict__ deg, int* __restrict__ offs, int n) {
  __shared__ int wsum[16];
  int carry = 0;  // only thread 0's copy is meaningful
  for (int base = 0; base < n; base += 1024) {
    int i = base + (int)threadIdx.x;
    int v = (i < n) ? deg[i] : 0;
    int lane = threadIdx.x & 63, wid = threadIdx.x >> 6;
    int x = v;
    #pragma unroll
    for (int off = 1; off < 64; off <<= 1) {
      int y = __shfl_up(x, off);
      if (lane >= off) x += y;
    }
    if (lane == 63) wsum[wid] = x;
    __syncthreads();
    if (threadIdx.x == 0) {
      int run = carry;
      #pragma unroll
      for (int w2 = 0; w2 < 16; w2++) { int tv = wsum[w2]; wsum[w2] = run; run += tv; }
      carry = run;
    }
    __syncthreads();
    if (i < n) offs[i] = x - v + wsum[wid];
    __syncthreads();  // protect wsum before next chunk overwrites it
  }
  if (threadIdx.x == 0) offs[n] = carry;
}

// ---------------- scatter edges into CSR-by-target (packed src+ea) ----------------
__global__ void scatter_kernel(const int* __restrict__ ei, const float* __restrict__ ea,
                               const float* __restrict__ ea_sum, const int* __restrict__ offs,
                               int* __restrict__ cursor, int2* __restrict__ csr_pack,
                               int E, int N) {
  int k = blockIdx.x * blockDim.x + threadIdx.x;
  if (k >= E + N) return;
  int s, t; float v;
  if (k < E) { s = ei[k]; t = ei[E + k]; v = ea[k]; }
  else       { s = t = k - E; v = ea_sum[0] * (1.0f / (float)E); }
  int pos = offs[t] + atomicAdd(&cursor[t], 1);
  csr_pack[pos] = make_int2(s, __float_as_int(v));
}

// ---------------- GATv2 layer 1, specialized for x of shape (N,1) ----------------
// Rank-1: out[c] = Wl[c]*T + bl[c] + bias[c], T = (sum a_e x_s) per head.
// All edge loads scalar (wave-uniform indices), batched fold-reduce, direct exp.
__global__ void gat1_kernel(const float* __restrict__ x,
    const int* __restrict__ offs, const int2* __restrict__ csr_pack,
    const float* __restrict__ Wl, const float* __restrict__ bl,
    const float* __restrict__ Wr, const float* __restrict__ br,
    const float* __restrict__ We, const float* __restrict__ att,
    const float* __restrict__ bias, float* __restrict__ outh, int N) {
  int t = (blockIdx.x * blockDim.x + threadIdx.x) >> 6;
  if (t >= N) return;
  int lane = threadIdx.x & 63;
  int c = lane * 2;
  float2 wl = *(const float2*)&Wl[c];
  float2 wr = *(const float2*)&Wr[c];
  float2 we = *(const float2*)&We[c];
  float2 at = *(const float2*)&att[c];
  float2 bl2 = *(const float2*)&bl[c];
  float2 br2 = *(const float2*)&br[c];
  float xt = x[t];
  float base0 = fmaf(xt, wr.x, br2.x + bl2.x);
  float base1 = fmaf(xt, wr.y, br2.y + bl2.y);
  int e0 = offs[t], e1 = offs[t + 1];
  int qlane = (lane >> 1) & 15;
  int bb = lane & 32;

  float den = 0.f, S1 = 0.f;
  for (int base = e0; base < e1; base += CHUNK) {
    float xs[CHUNK], eav[CHUNK];
    #pragma unroll
    for (int q = 0; q < CHUNK; q++) {
      int e = base + q;
      int ec = __builtin_amdgcn_readfirstlane(e < e1 ? e : e1 - 1);
      int2 pk = csr_pack[ec];
      int s = __builtin_amdgcn_readfirstlane(pk.x);
      eav[q] = __int_as_float(pk.y);
      xs[q] = x[s];
    }
    float pr[CHUNK];
    #pragma unroll
    for (int q = 0; q < CHUNK; q++) {
      float m0 = fmaf(xs[q], wl.x, fmaf(eav[q], we.x, base0));
      float m1 = fmaf(xs[q], wl.y, fmaf(eav[q], we.y, base1));
      float l0 = fmaxf(m0, NEG_SLOPE * m0);   // leaky-relu (slope<1)
      float l1 = fmaxf(m1, NEG_SLOPE * m1);
      pr[q] = fmaf(l0, at.x, l1 * at.y);
    }
    FOLD_STEP(16, 8) FOLD_STEP(8, 4) FOLD_STEP(4, 2) FOLD_STEP(2, 1)
    pr[0] += __shfl_xor(pr[0], 1);
    float wgt = (base + qlane < e1) ? __expf(pr[0]) : 0.f;  // direct exp, no max-sub
    #pragma unroll
    for (int q = 0; q < CHUNK; q++) {
      float wq = __shfl(wgt, bb + 2 * q);     // head-local broadcast of edge q's weight
      den += wq;
      S1 = fmaf(wq, xs[q], S1);
    }
  }
  float T = S1 / den;
  float2 bv = *(const float2*)&bias[c];
  float o0 = fmaxf(fmaf(wl.x, T, bl2.x + bv.x), 0.f);
  float o1 = fmaxf(fmaf(wl.y, T, bl2.y + bv.y), 0.f);
  *(float2*)&outh[(size_t)t * HCC + c] = make_float2(o0, o1);
}

// ---------------- GATv2 layer 2: one wave per node ----------------
// Batched fold-reduce (1 shfl+add per edge), distributed exp (1 v_exp per 16
// edges), scalar csr loads + SGPR-base row gathers, no max-sub.
__global__ void gat2_kernel(const float* __restrict__ xl, const float* __restrict__ xr,
    const int* __restrict__ offs, const int2* __restrict__ csr_pack,
    const float* __restrict__ We, const float* __restrict__ att,
    const float* __restrict__ bias, float* __restrict__ outh, int N) {
  int t = (blockIdx.x * blockDim.x + threadIdx.x) >> 6;
  if (t >= N) return;
  int lane = threadIdx.x & 63;
  int c = lane * 2;
  float2 xrv = *(const float2*)&xr[(size_t)t * HCC + c];
  float2 wev = *(const float2*)&We[c];
  float2 atv = *(const float2*)&att[c];
  int e0 = offs[t], e1 = offs[t + 1];
  int qlane = (lane >> 1) & 15;
  int bb = lane & 32;

  float den = 0.f, a0 = 0.f, a1 = 0.f;
  for (int base = e0; base < e1; base += CHUNK) {
    float2 xj[CHUNK]; float eav[CHUNK];
    #pragma unroll
    for (int q = 0; q < CHUNK; q++) {
      int e = base + q;
      int ec = __builtin_amdgcn_readfirstlane(e < e1 ? e : e1 - 1);
      int2 pk = csr_pack[ec];
      int s = __builtin_amdgcn_readfirstlane(pk.x);
      eav[q] = __int_as_float(pk.y);
      xj[q] = *(const float2*)&xl[(size_t)s * HCC + c];  // SGPR base + lane offset
    }
    float pr[CHUNK];
    #pragma unroll
    for (int q = 0; q < CHUNK; q++) {
      float m0 = fmaf(eav[q], wev.x, xrv.x + xj[q].x);
      float m1 = fmaf(eav[q], wev.y, xrv.y + xj[q].y);
      float l0 = fmaxf(m0, NEG_SLOPE * m0);
      float l1 = fmaxf(m1, NEG_SLOPE * m1);
      pr[q] = fmaf(l0, atv.x, l1 * atv.y);
    }
    FOLD_STEP(16, 8) FOLD_STEP(8, 4) FOLD_STEP(4, 2) FOLD_STEP(2, 1)
    pr[0] += __shfl_xor(pr[0], 1);
    float wgt = (base + qlane < e1) ? __expf(pr[0]) : 0.f;
    #pragma unroll
    for (int q = 0; q < CHUNK; q++) {
      float wq = __shfl(wgt, bb + 2 * q);
      den += wq;
      a0 = fmaf(wq, xj[q].x, a0);
      a1 = fmaf(wq, xj[q].y, a1);
    }
  }
  float inv = 1.0f / den;
  float2 bv = *(const float2*)&bias[c];
  float o0 = fmaxf(fmaf(a0, inv, bv.x), 0.f);
  float o1 = fmaxf(fmaf(a1, inv, bv.y), 0.f);
  *(float2*)&outh[(size_t)t * HCC + c] = make_float2(o0, o1);
}

// ---------------- layer-2 transforms: h1(N,128) @ {Wl,Wr}(128,128) ----------------
// 64 nodes/block, 512 threads, 48 KB LDS (3 blocks/CU): W re-staged 4x less.
__global__ __launch_bounds__(512) void l2_transform_kernel(const float* __restrict__ h,
    const float* __restrict__ Wl, const float* __restrict__ bl,
    const float* __restrict__ Wr, const float* __restrict__ br,
    float* __restrict__ xl, float* __restrict__ xr, int N) {
  __shared__ float hs[64][HCC];      // 32 KB
  __shared__ float Ws[2][16][HCC];   // 16 KB per k-chunk
  int tid = threadIdx.x;
  int nbase = blockIdx.x * 64;
  for (int i = tid; i < 64 * 32; i += 512) {
    int nr = i >> 5, col = (i & 31) * 4;
    int gn = nbase + nr;
    float4 v = (gn < N) ? *(const float4*)&h[(size_t)gn * HCC + col] : make_float4(0,0,0,0);
    *(float4*)&hs[nr][col] = v;
  }
  int slot = tid >> 5;          // 0..15
  int c0 = (tid & 31) * 4;
  float acc[4][8];
  #pragma unroll
  for (int r = 0; r < 4; r++)
    #pragma unroll
    for (int q = 0; q < 8; q++) acc[r][q] = 0.f;

  for (int kb = 0; kb < 8; kb++) {
    __syncthreads();
    #pragma unroll
    for (int i = tid; i < 1024; i += 512) {
      int mat = i >> 9;
      int idx = i & 511;
      int krow = idx >> 5, col = (idx & 31) * 4;
      const float* src = mat ? Wr : Wl;
      *(float4*)&Ws[mat][krow][col] = *(const float4*)&src[(size_t)(kb * 16 + krow) * HCC + col];
    }
    __syncthreads();
    for (int k2 = 0; k2 < 16; k2++) {
      float4 wl4 = *(const float4*)&Ws[0][k2][c0];
      float4 wr4 = *(const float4*)&Ws[1][k2][c0];
      int kk = kb * 16 + k2;
      #pragma unroll
      for (int r = 0; r < 4; r++) {
        float hv = hs[slot + 16 * r][kk];
        acc[r][0] = fmaf(hv, wl4.x, acc[r][0]);
        acc[r][1] = fmaf(hv, wl4.y, acc[r][1]);
        acc[r][2] = fmaf(hv, wl4.z, acc[r][2]);
        acc[r][3] = fmaf(hv, wl4.w, acc[r][3]);
        acc[r][4] = fmaf(hv, wr4.x, acc[r][4]);
        acc[r][5] = fmaf(hv, wr4.y, acc[r][5]);
        acc[r][6] = fmaf(hv, wr4.z, acc[r][6]);
        acc[r][7] = fmaf(hv, wr4.w, acc[r][7]);
      }
    }
  }
  float4 blv = *(const float4*)&bl[c0];
  float4 brv = *(const float4*)&br[c0];
  #pragma unroll
  for (int r = 0; r < 4; r++) {
    int gn = nbase + slot + 16 * r;
    if (gn < N) {
      float4 o1 = make_float4(acc[r][0] + blv.x, acc[r][1] + blv.y, acc[r][2] + blv.z, acc[r][3] + blv.w);
      float4 o2 = make_float4(acc[r][4] + brv.x, acc[r][5] + brv.y, acc[r][6] + brv.z, acc[r][7] + brv.w);
      *(float4*)&xl[(size_t)gn * HCC + c0] = o1;
      *(float4*)&xr[(size_t)gn * HCC + c0] = o2;
    }
  }
}

// ---------------- msg_emb^T = (message @ fc1_W + fc1_b)^T  -> [128][256] ----------------
__global__ void msg_gemm_kernel(const float* __restrict__ msg, const float* __restrict__ W,
                                const float* __restrict__ b, float* __restrict__ memb_t) {
  int r = blockIdx.x, c = threadIdx.x;
  const float* mrow = &msg[(size_t)r * HCC];
  float acc = b[c];
  #pragma unroll 8
  for (int k = 0; k < HCC; k++) acc = fmaf(mrow[k], W[(size_t)k * HCC + c], acc);
  memb_t[(size_t)c * 256 + r] = acc;
}

// ---------------- logits = h @ memb^T; row softmax ----------------
__global__ __launch_bounds__(256) void logits_softmax_kernel(
    const float* __restrict__ h, const float* __restrict__ memb_t,
    float* __restrict__ out, int N) {
  __shared__ float hs[64][HCC];   // 32 KB
  __shared__ float ms[16][256];   // 16 KB  (k-chunk of memb_t)
  int tid = threadIdx.x;
  int nbase = blockIdx.x * 64;
  for (int i = tid; i < 64 * 32; i += 256) {
    int nr = i >> 5, col = (i & 31) * 4;
    int gn = nbase + nr;
    float4 v = (gn < N) ? *(const float4*)&h[(size_t)gn * HCC + col] : make_float4(0, 0, 0, 0);
    *(float4*)&hs[nr][col] = v;
  }
  int ty = tid >> 5, tx = tid & 31;
  float2 acc[8][4];
  #pragma unroll
  for (int i = 0; i < 8; i++)
    #pragma unroll
    for (int j = 0; j < 4; j++) acc[i][j] = make_float2(0.f, 0.f);

  for (int kb = 0; kb < 8; kb++) {
    __syncthreads();
    for (int i = tid; i < 1024; i += 256) {
      int kr = i >> 6, col = (i & 63) * 4;
      *(float4*)&ms[kr][col] = *(const float4*)&memb_t[(size_t)(kb * 16 + kr) * 256 + col];
    }
    __syncthreads();
    for (int kk = 0; kk < 16; kk += 4) {
      float4 a[8];
      #pragma unroll
      for (int i = 0; i < 8; i++) a[i] = *(const float4*)&hs[ty * 8 + i][kb * 16 + kk];
      #pragma unroll
      for (int q = 0; q < 4; q++) {
        float2 bv[4];
        #pragma unroll
        for (int j = 0; j < 4; j++) bv[j] = *(const float2*)&ms[kk + q][j * 64 + tx * 2];
        #pragma unroll
        for (int i = 0; i < 8; i++) {
          float av = (q == 0) ? a[i].x : (q == 1) ? a[i].y : (q == 2) ? a[i].z : a[i].w;
          #pragma unroll
          for (int j = 0; j < 4; j++) {
            acc[i][j].x = fmaf(av, bv[j].x, acc[i][j].x);
            acc[i][j].y = fmaf(av, bv[j].y, acc[i][j].y);
          }
        }
      }
    }
  }

  #pragma unroll
  for (int i = 0; i < 8; i++) {
    int gn = nbase + ty * 8 + i;
    float m = fmaxf(acc[i][0].x, acc[i][0].y);
    #pragma unroll
    for (int j = 1; j < 4; j++) m = fmaxf(m, fmaxf(acc[i][j].x, acc[i][j].y));
    #pragma unroll
    for (int off = 1; off < 32; off <<= 1) m = fmaxf(m, __shfl_xor(m, off));
    float2 e[4]; float s = 0.f;
    #pragma unroll
    for (int j = 0; j < 4; j++) {
      e[j].x = expf(acc[i][j].x - m);
      e[j].y = expf(acc[i][j].y - m);
      s += e[j].x + e[j].y;
    }
    #pragma unroll
    for (int off = 1; off < 32; off <<= 1) s += __shfl_xor(s, off);
    float inv = 1.0f / s;
    if (gn < N) {
      #pragma unroll
      for (int j = 0; j < 4; j++) {
        float2 o = make_float2(e[j].x * inv, e[j].y * inv);
        *(float2*)&out[(size_t)gn * 256 + j * 64 + tx * 2] = o;
      }
    }
  }
}

extern "C" void kernel_launch(void* const* d_in, const int* in_sizes, int n_in,
                              void* d_out, int out_size, void* d_ws, size_t ws_size,
                              hipStream_t stream) {
  (void)n_in; (void)out_size; (void)ws_size;
  const float* message  = (const float*)d_in[0];
  const float* x        = (const float*)d_in[1];
  const float* edge_attr= (const float*)d_in[2];
  const float* c1_Wl   = (const float*)d_in[3];
  const float* c1_bl   = (const float*)d_in[4];
  const float* c1_Wr   = (const float*)d_in[5];
  const float* c1_br   = (const float*)d_in[6];
  const float* c1_We   = (const float*)d_in[7];
  const float* c1_att  = (const float*)d_in[8];
  const float* c1_bias = (const float*)d_in[9];
  const float* c2_Wl   = (const float*)d_in[10];
  const float* c2_bl   = (const float*)d_in[11];
  const float* c2_Wr   = (const float*)d_in[12];
  const float* c2_br   = (const float*)d_in[13];
  const float* c2_We   = (const float*)d_in[14];
  const float* c2_att  = (const float*)d_in[15];
  const float* c2_bias = (const float*)d_in[16];
  const float* fc1_W   = (const float*)d_in[17];
  const float* fc1_b   = (const float*)d_in[18];
  const int* edge_index = (const int*)d_in[19];

  const int N = in_sizes[1];          // 50000
  const int E = in_sizes[2];          // 500000
  const int Et = E + N;
  const int B = in_sizes[0] / HCC;    // 256
  float* out = (float*)d_out;

  char* wsb = (char*)d_ws;
  size_t woff = 0;
  auto alloc = [&](size_t bytes) -> void* {
    void* p = wsb + woff;
    woff += (bytes + 255) & ~(size_t)255;
    return p;
  };
  float* xl     = (float*)alloc((size_t)N * HCC * 4);
  float* xr     = (float*)alloc((size_t)N * HCC * 4);
  float* hb     = (float*)alloc((size_t)N * HCC * 4);
  float* memb_t = (float*)alloc((size_t)B * HCC * 4);
  float* ea_sum = (float*)alloc(256);
  int* deg      = (int*)alloc((size_t)N * 4);
  int* offs     = (int*)alloc((size_t)(N + 1) * 4);
  int* cursor   = (int*)alloc((size_t)N * 4);
  int2* csr_pack= (int2*)alloc((size_t)Et * 8);

  hipMemsetAsync(ea_sum, 0, 4, stream);
  hipMemsetAsync(deg, 0, (size_t)N * 4, stream);
  hipMemsetAsync(cursor, 0, (size_t)N * 4, stream);

  ea_reduce_kernel<<<256, 256, 0, stream>>>(edge_attr, ea_sum, E);
  deg_count_kernel<<<(Et + 255) / 256, 256, 0, stream>>>(edge_index, deg, E, N);
  scan_kernel<<<1, 1024, 0, stream>>>(deg, offs, N);
  scatter_kernel<<<(Et + 255) / 256, 256, 0, stream>>>(edge_index, edge_attr, ea_sum,
                                                       offs, cursor, csr_pack, E, N);
  gat1_kernel<<<(N + 3) / 4, 256, 0, stream>>>(x, offs, csr_pack,
                                               c1_Wl, c1_bl, c1_Wr, c1_br,
                                               c1_We, c1_att, c1_bias, hb, N);
  l2_transform_kernel<<<(N + 63) / 64, 512, 0, stream>>>(hb, c2_Wl, c2_bl, c2_Wr, c2_br,
                                                         xl, xr, N);
  gat2_kernel<<<(N + 3) / 4, 256, 0, stream>>>(xl, xr, offs, csr_pack,
                                               c2_We, c2_att, c2_bias, hb, N);
  msg_gemm_kernel<<<B, HCC, 0, stream>>>(message, fc1_W, fc1_b, memb_t);
  logits_softmax_kernel<<<(N + 63) / 64, 256, 0, stream>>>(hb, memb_t, out, N);
}